// Round 2
// baseline (625.226 us; speedup 1.0000x reference)
//
#include <hip/hip_runtime.h>

typedef _Float16 f16;
typedef _Float16 f16x8 __attribute__((ext_vector_type(8)));
typedef float    f32x4 __attribute__((ext_vector_type(4)));
typedef f16x8 f16x8_a __attribute__((may_alias));
typedef f16   f16_a   __attribute__((may_alias));

#define NN 100000
#define NE 1000000
#define NT 31250            // NE/32 edge tiles (exact)
#define EK_BLOCKS 512
#define EK_WAVES (EK_BLOCKS * 4)

static __device__ __forceinline__ f32x4 mfma16(f16x8 a, f16x8 b, f32x4 c) {
  return __builtin_amdgcn_mfma_f32_16x16x32_f16(a, b, c, 0, 0, 0);
}

static __device__ __forceinline__ f16x8 zero8() {
  f16x8 z;
#pragma unroll
  for (int j = 0; j < 8; ++j) z[j] = (f16)0.f;
  return z;
}

static __device__ __forceinline__ f16x8 relu8(f16x8 x) {
  f16x8 r;
#pragma unroll
  for (int j = 0; j < 8; ++j) r[j] = x[j] > (f16)0.f ? x[j] : (f16)0.f;
  return r;
}

// ---- LDS staging with XOR swizzle (byte ^= (row&7)<<4), rows = 256B ----
template<int RB_LOG2, int SZ>
static __device__ __forceinline__ void load_weights(const f16* __restrict__ gw, char* lds) {
  const char* src = (const char*)gw;
#pragma unroll
  for (int g = threadIdx.x; g < SZ / 16; g += 256) {
    int byte = g << 4;
    int row  = byte >> RB_LOG2;
    int dstb = byte ^ ((row & 7) << 4);
    f16x8 v = *(const f16x8_a*)(src + byte);
    *(f16x8_a*)(lds + dstb) = v;
  }
}

template<int RB_LOG2>
static __device__ __forceinline__ f16x8 read_b(const char* lds, int n, int kbyte) {
  int byte = ((n << RB_LOG2) + kbyte) ^ ((n & 7) << 4);
  return *(const f16x8_a*)(lds + byte);
}

// per-wave activation tile: 32 rows x 128 f16 (256B rows), swizzled
static __device__ __forceinline__ f16x8 act_read(const char* act, int base, int m, int kbyte) {
  int byte = (base + m * 256 + kbyte) ^ ((m & 7) << 4);
  return *(const f16x8_a*)(act + byte);
}

static __device__ __forceinline__ void act_write(char* act, int base, int m, int col, f16 v) {
  int byte = (base + m * 256 + col * 2) ^ ((m & 7) << 4);
  *(f16_a*)(act + byte) = v;
}

// ---------------- prep kernels ----------------
__global__ void transpose_w(const float* __restrict__ src, f16* __restrict__ dst,
                            int K, int N, int kOff, int ld) {
  int i = blockIdx.x * 256 + threadIdx.x;
  if (i >= N * K) return;
  int n = i / K, k = i - n * K;
  dst[i] = (f16)src[(size_t)(kOff + k) * ld + n];
}

// dstT[j*128 + i] = (f16) sum_k A[i][k] * Wp1[(rowOff+k)][j]   (A: [128][128] row-major)
__global__ void mm_fold(const float* __restrict__ A, const float* __restrict__ Wp1,
                        int rowOff, f16* __restrict__ dstT) {
  int g = blockIdx.x * 256 + threadIdx.x;   // 0..16383
  int i = g >> 7, j = g & 127;
  float s = 0.f;
#pragma unroll 8
  for (int k = 0; k < 128; ++k) s += A[i * 128 + k] * Wp1[(size_t)(rowOff + k) * 128 + j];
  dstT[j * 128 + i] = (f16)s;
}

// bfold[j] = bp1[j] + bn2@Wp1a + bn2@Wp1b + be2@Wp1c  (column j)
__global__ void bias_fold(const float* __restrict__ bp1, const float* __restrict__ bn2,
                          const float* __restrict__ be2, const float* __restrict__ Wp1,
                          float* __restrict__ bfold) {
  int j = threadIdx.x;  // 128 threads
  float s = bp1[j];
#pragma unroll 8
  for (int k = 0; k < 128; ++k)
    s += bn2[k] * (Wp1[(size_t)k * 128 + j] + Wp1[(size_t)(128 + k) * 128 + j]);
#pragma unroll 8
  for (int k = 0; k < 128; ++k)
    s += be2[k] * Wp1[(size_t)(256 + k) * 128 + j];
  bfold[j] = s;
}

// ---------------- node side: nf -> h1n -> PA (=h1n@Wn2a + bfold), PB (=h1n@Wn2b) ----------------
__global__ __launch_bounds__(256, 2) void node_kernel(
    const float* __restrict__ nf, const f16* __restrict__ WnT1, const float* __restrict__ bn1,
    const f16* __restrict__ Wn2aT, const f16* __restrict__ Wn2bT, const float* __restrict__ bfold,
    f16* __restrict__ PA, f16* __restrict__ PB) {
  __shared__ char wbuf[32768];
  __shared__ char act[32768];
  const int tid = threadIdx.x, w = tid >> 6, lane = tid & 63;
  const int c = lane & 15, kb = lane >> 4;
  const int base = blockIdx.x * 128 + w * 32;
  const int abase = w * 8192;

  load_weights<8, 32768>(WnT1, wbuf);
  __syncthreads();

  // phase 1: h1n = relu(nf @ Wn1 + bn1)
  {
    f16x8 a[2][4];
#pragma unroll
    for (int rt = 0; rt < 2; ++rt) {
      int r = base + rt * 16 + c; r = r < NN ? r : 0;
      const float* p = nf + (size_t)r * 128 + kb * 8;
#pragma unroll
      for (int ks = 0; ks < 4; ++ks) {
        float4 x0 = *(const float4*)(p + ks * 32);
        float4 x1 = *(const float4*)(p + ks * 32 + 4);
        f16x8 t;
        t[0]=(f16)x0.x; t[1]=(f16)x0.y; t[2]=(f16)x0.z; t[3]=(f16)x0.w;
        t[4]=(f16)x1.x; t[5]=(f16)x1.y; t[6]=(f16)x1.z; t[7]=(f16)x1.w;
        a[rt][ks] = t;
      }
    }
    f32x4 acc[2][8];
#pragma unroll
    for (int nt = 0; nt < 8; ++nt) {
      float bb = bn1[nt * 16 + c];
      acc[0][nt] = f32x4{bb, bb, bb, bb};
      acc[1][nt] = f32x4{bb, bb, bb, bb};
    }
#pragma unroll
    for (int ks = 0; ks < 4; ++ks)
#pragma unroll
      for (int nt = 0; nt < 8; ++nt) {
        f16x8 b = read_b<8>(wbuf, nt * 16 + c, ks * 64 + kb * 16);
        acc[0][nt] = mfma16(a[0][ks], b, acc[0][nt]);
        acc[1][nt] = mfma16(a[1][ks], b, acc[1][nt]);
      }
#pragma unroll
    for (int rt = 0; rt < 2; ++rt)
#pragma unroll
      for (int nt = 0; nt < 8; ++nt)
#pragma unroll
        for (int r = 0; r < 4; ++r) {
          float v = acc[rt][nt][r];
          v = v > 0.f ? v : 0.f;
          act_write(act, abase, rt * 16 + kb * 4 + r, nt * 16 + c, (f16)v);
        }
  }

  // phase 2: PA = h1n @ Wn2a + bfold
  __syncthreads();
  load_weights<8, 32768>(Wn2aT, wbuf);
  __syncthreads();
  {
    f32x4 acc[2][8];
#pragma unroll
    for (int nt = 0; nt < 8; ++nt) {
      float bb = bfold[nt * 16 + c];
      acc[0][nt] = f32x4{bb, bb, bb, bb};
      acc[1][nt] = f32x4{bb, bb, bb, bb};
    }
#pragma unroll
    for (int ks = 0; ks < 4; ++ks) {
      f16x8 a0 = act_read(act, abase, c,      ks * 64 + kb * 16);
      f16x8 a1 = act_read(act, abase, 16 + c, ks * 64 + kb * 16);
#pragma unroll
      for (int nt = 0; nt < 8; ++nt) {
        f16x8 b = read_b<8>(wbuf, nt * 16 + c, ks * 64 + kb * 16);
        acc[0][nt] = mfma16(a0, b, acc[0][nt]);
        acc[1][nt] = mfma16(a1, b, acc[1][nt]);
      }
    }
#pragma unroll
    for (int rt = 0; rt < 2; ++rt)
#pragma unroll
      for (int nt = 0; nt < 8; ++nt)
#pragma unroll
        for (int r = 0; r < 4; ++r) {
          int row = base + rt * 16 + kb * 4 + r;
          if (row < NN) PA[(size_t)row * 128 + nt * 16 + c] = (f16)acc[rt][nt][r];
        }
  }

  // phase 3: PB = h1n @ Wn2b
  __syncthreads();
  load_weights<8, 32768>(Wn2bT, wbuf);
  __syncthreads();
  {
    f32x4 acc[2][8];
#pragma unroll
    for (int nt = 0; nt < 8; ++nt) {
      acc[0][nt] = f32x4{0.f, 0.f, 0.f, 0.f};
      acc[1][nt] = f32x4{0.f, 0.f, 0.f, 0.f};
    }
#pragma unroll
    for (int ks = 0; ks < 4; ++ks) {
      f16x8 a0 = act_read(act, abase, c,      ks * 64 + kb * 16);
      f16x8 a1 = act_read(act, abase, 16 + c, ks * 64 + kb * 16);
#pragma unroll
      for (int nt = 0; nt < 8; ++nt) {
        f16x8 b = read_b<8>(wbuf, nt * 16 + c, ks * 64 + kb * 16);
        acc[0][nt] = mfma16(a0, b, acc[0][nt]);
        acc[1][nt] = mfma16(a1, b, acc[1][nt]);
      }
    }
#pragma unroll
    for (int rt = 0; rt < 2; ++rt)
#pragma unroll
      for (int nt = 0; nt < 8; ++nt)
#pragma unroll
        for (int r = 0; r < 4; ++r) {
          int row = base + rt * 16 + kb * 4 + r;
          if (row < NN) PB[(size_t)row * 128 + nt * 16 + c] = (f16)acc[rt][nt][r];
        }
  }
}

// ---------------- persistent fused edge kernel (no barriers in loop) ----------------
__global__ __launch_bounds__(256, 2) void edge_kernel(
    const float* __restrict__ ef, const int* __restrict__ eidx,
    const f16* __restrict__ WeT1, const float* __restrict__ be1,
    const f16* __restrict__ WCT, const f16* __restrict__ WpT2g,
    const float* __restrict__ bp2, const float* __restrict__ Wp3, const float* __restrict__ bp3,
    const f16* __restrict__ PA, const f16* __restrict__ PB,
    float* __restrict__ out) {
  __shared__ char wc[32768];
  __shared__ char wp2[16384];
  __shared__ char act[32768];
  const int tid = threadIdx.x, w = tid >> 6, lane = tid & 63;
  const int c = lane & 15, kb = lane >> 4;
  const int abase = w * 8192;

  load_weights<8, 32768>(WCT, wc);
  load_weights<8, 16384>(WpT2g, wp2);
  __syncthreads();   // the only barrier

  // hoisted invariants
  f16x8 w1frag[8];
  float bias_e1[8], bias_p2[4], w3[4];
#pragma unroll
  for (int nt = 0; nt < 8; ++nt) {
    w1frag[nt] = *(const f16x8_a*)(WeT1 + (nt * 16 + c) * 16 + (kb & 1) * 8);
    bias_e1[nt] = be1[nt * 16 + c];
  }
#pragma unroll
  for (int nt = 0; nt < 4; ++nt) { bias_p2[nt] = bp2[nt * 16 + c]; w3[nt] = Wp3[nt * 16 + c]; }
  const float b3 = bp3[0];

  const int gw = blockIdx.x * 4 + w;
  for (int t = gw; t < NT; t += EK_WAVES) {
    const int ebase = t * 32;
    const int e0 = ebase + c, e1 = e0 + 16;
    const int s0 = eidx[e0],      s1 = eidx[e1];
    const int d0 = eidx[NE + e0], d1 = eidx[NE + e1];

    // issue PA/PB gathers early; consumed in P2 (E1+PE hide latency)
    f16x8 gpa0[4], gpa1[4], gpb0[4], gpb1[4];
    {
      const f16* p0 = PA + (size_t)s0 * 128 + kb * 8;
      const f16* p1 = PA + (size_t)s1 * 128 + kb * 8;
      const f16* q0 = PB + (size_t)d0 * 128 + kb * 8;
      const f16* q1 = PB + (size_t)d1 * 128 + kb * 8;
#pragma unroll
      for (int ks = 0; ks < 4; ++ks) {
        gpa0[ks] = *(const f16x8_a*)(p0 + ks * 32);
        gpa1[ks] = *(const f16x8_a*)(p1 + ks * 32);
        gpb0[ks] = *(const f16x8_a*)(q0 + ks * 32);
        gpb1[ks] = *(const f16x8_a*)(q1 + ks * 32);
      }
    }

    // ---- E1: h1e = relu(ef @ We1 + be1) ----
    {
      f16x8 ae[2];
#pragma unroll
      for (int rt = 0; rt < 2; ++rt) {
        f16x8 v = zero8();
        if (kb < 2) {
          const float* p = ef + (size_t)(ebase + rt * 16 + c) * 16 + kb * 8;
          float4 x0 = *(const float4*)(p);
          float4 x1 = *(const float4*)(p + 4);
          v[0]=(f16)x0.x; v[1]=(f16)x0.y; v[2]=(f16)x0.z; v[3]=(f16)x0.w;
          v[4]=(f16)x1.x; v[5]=(f16)x1.y; v[6]=(f16)x1.z; v[7]=(f16)x1.w;
        }
        ae[rt] = v;
      }
      f32x4 acc[2][8];
#pragma unroll
      for (int nt = 0; nt < 8; ++nt) {
        acc[0][nt] = f32x4{bias_e1[nt], bias_e1[nt], bias_e1[nt], bias_e1[nt]};
        acc[1][nt] = acc[0][nt];
      }
#pragma unroll
      for (int nt = 0; nt < 8; ++nt) {
        acc[0][nt] = mfma16(ae[0], w1frag[nt], acc[0][nt]);
        acc[1][nt] = mfma16(ae[1], w1frag[nt], acc[1][nt]);
      }
#pragma unroll
      for (int rt = 0; rt < 2; ++rt)
#pragma unroll
        for (int nt = 0; nt < 8; ++nt)
#pragma unroll
          for (int r = 0; r < 4; ++r) {
            float v = acc[rt][nt][r];
            v = v > 0.f ? v : 0.f;
            act_write(act, abase, rt * 16 + kb * 4 + r, nt * 16 + c, (f16)v);
          }
    }

    // ---- PE: pe = h1e @ WC (raw, no bias) ----
    {
      f32x4 acc[2][8];
#pragma unroll
      for (int nt = 0; nt < 8; ++nt) {
        acc[0][nt] = f32x4{0.f, 0.f, 0.f, 0.f};
        acc[1][nt] = f32x4{0.f, 0.f, 0.f, 0.f};
      }
#pragma unroll
      for (int ks = 0; ks < 4; ++ks) {
        f16x8 a0 = act_read(act, abase, c,      ks * 64 + kb * 16);
        f16x8 a1 = act_read(act, abase, 16 + c, ks * 64 + kb * 16);
#pragma unroll
        for (int nt = 0; nt < 8; ++nt) {
          f16x8 b = read_b<8>(wc, nt * 16 + c, ks * 64 + kb * 16);
          acc[0][nt] = mfma16(a0, b, acc[0][nt]);
          acc[1][nt] = mfma16(a1, b, acc[1][nt]);
        }
      }
#pragma unroll
      for (int rt = 0; rt < 2; ++rt)
#pragma unroll
        for (int nt = 0; nt < 8; ++nt)
#pragma unroll
          for (int r = 0; r < 4; ++r)
            act_write(act, abase, rt * 16 + kb * 4 + r, nt * 16 + c, (f16)acc[rt][nt][r]);
    }

    // ---- P2: h2 = relu(pe + PA[src] + PB[dst]) @ Wp2 + bp2 ----
    f32x4 accq[2][4];
#pragma unroll
    for (int nt = 0; nt < 4; ++nt) {
      accq[0][nt] = f32x4{bias_p2[nt], bias_p2[nt], bias_p2[nt], bias_p2[nt]};
      accq[1][nt] = accq[0][nt];
    }
    {
      f16x8 ap0[4], ap1[4];
#pragma unroll
      for (int ks = 0; ks < 4; ++ks) {
        f16x8 x0 = act_read(act, abase, c,      ks * 64 + kb * 16);
        f16x8 x1 = act_read(act, abase, 16 + c, ks * 64 + kb * 16);
        ap0[ks] = relu8(x0 + gpa0[ks] + gpb0[ks]);
        ap1[ks] = relu8(x1 + gpa1[ks] + gpb1[ks]);
      }
#pragma unroll
      for (int ks = 0; ks < 4; ++ks)
#pragma unroll
        for (int nt = 0; nt < 4; ++nt) {
          f16x8 b = read_b<8>(wp2, nt * 16 + c, ks * 64 + kb * 16);
          accq[0][nt] = mfma16(ap0[ks], b, accq[0][nt]);
          accq[1][nt] = mfma16(ap1[ks], b, accq[1][nt]);
        }
    }

    // ---- P3: relu, dot Wp3, sigmoid ----
#pragma unroll
    for (int rt = 0; rt < 2; ++rt) {
#pragma unroll
      for (int r = 0; r < 4; ++r) {
        float s = 0.f;
#pragma unroll
        for (int nt = 0; nt < 4; ++nt) {
          float h = accq[rt][nt][r];
          h = h > 0.f ? h : 0.f;
          s += h * w3[nt];
        }
        s += __shfl_xor(s, 1, 64);
        s += __shfl_xor(s, 2, 64);
        s += __shfl_xor(s, 4, 64);
        s += __shfl_xor(s, 8, 64);
        int m = ebase + rt * 16 + kb * 4 + r;
        if (c == r) {
          out[m] = 1.f / (1.f + __expf(-(s + b3)));
        }
      }
    }
  }
}

extern "C" void kernel_launch(void* const* d_in, const int* in_sizes, int n_in,
                              void* d_out, int out_size, void* d_ws, size_t ws_size,
                              hipStream_t stream) {
  const float* nf  = (const float*)d_in[0];
  const int*   ei  = (const int*)  d_in[1];
  const float* ef  = (const float*)d_in[2];
  const float* Wn1 = (const float*)d_in[3];
  const float* bn1 = (const float*)d_in[4];
  const float* Wn2 = (const float*)d_in[5];
  const float* bn2 = (const float*)d_in[6];
  const float* We1 = (const float*)d_in[7];
  const float* be1 = (const float*)d_in[8];
  const float* We2 = (const float*)d_in[9];
  const float* be2 = (const float*)d_in[10];
  const float* Wp1 = (const float*)d_in[11];
  const float* bp1 = (const float*)d_in[12];
  const float* Wp2 = (const float*)d_in[13];
  const float* bp2 = (const float*)d_in[14];
  const float* Wp3 = (const float*)d_in[15];
  const float* bp3 = (const float*)d_in[16];

  char* ws = (char*)d_ws;
  f16*   WnT1  = (f16*)(ws);                 // 32768 B
  f16*   Wn2aT = (f16*)(ws + 32768);         // 32768 B
  f16*   Wn2bT = (f16*)(ws + 65536);         // 32768 B
  f16*   WeT1  = (f16*)(ws + 98304);         // 4096 B
  f16*   WCT   = (f16*)(ws + 102400);        // 32768 B
  f16*   WpT2  = (f16*)(ws + 135168);        // 16384 B
  float* bfold = (float*)(ws + 151552);      // 512 B
  f16*   PA    = (f16*)(ws + 155648);        // 25,600,000 B
  f16*   PB    = (f16*)(ws + 155648 + 25600000);

  transpose_w<<<64, 256, 0, stream>>>(Wn1, WnT1, 128, 128, 0, 128);
  transpose_w<<<8,  256, 0, stream>>>(We1, WeT1, 16,  128, 0, 128);
  transpose_w<<<32, 256, 0, stream>>>(Wp2, WpT2, 128, 64, 0, 64);
  mm_fold<<<64, 256, 0, stream>>>(Wn2, Wp1, 0,   Wn2aT);
  mm_fold<<<64, 256, 0, stream>>>(Wn2, Wp1, 128, Wn2bT);
  mm_fold<<<64, 256, 0, stream>>>(We2, Wp1, 256, WCT);
  bias_fold<<<1, 128, 0, stream>>>(bp1, bn2, be2, Wp1, bfold);

  node_kernel<<<782, 256, 0, stream>>>(nf, WnT1, bn1, Wn2aT, Wn2bT, bfold, PA, PB);
  edge_kernel<<<EK_BLOCKS, 256, 0, stream>>>(ef, ei, WeT1, be1, WCT, WpT2,
                                             bp2, Wp3, bp3, PA, PB, (float*)d_out);
}

// Round 3
// 476.925 us; speedup vs baseline: 1.3110x; 1.3110x over previous
//
#include <hip/hip_runtime.h>

typedef _Float16 f16;
typedef _Float16 f16x8 __attribute__((ext_vector_type(8)));
typedef float    f32x4 __attribute__((ext_vector_type(4)));
typedef float    fv4   __attribute__((ext_vector_type(4)));
typedef f16x8 f16x8_a __attribute__((may_alias));
typedef f16   f16_a   __attribute__((may_alias));
typedef fv4   fv4_a   __attribute__((may_alias));

#define NN 100000
#define NE 1000000
#define NT_TILES 31250        // NE/32
#define EK_BLOCKS 256
#define NW (EK_BLOCKS * 4)    // 1024 waves

static __device__ __forceinline__ f32x4 mfma16(f16x8 a, f16x8 b, f32x4 c) {
  return __builtin_amdgcn_mfma_f32_16x16x32_f16(a, b, c, 0, 0, 0);
}

static __device__ __forceinline__ f16x8 zero8() {
  f16x8 z;
#pragma unroll
  for (int j = 0; j < 8; ++j) z[j] = (f16)0.f;
  return z;
}

static __device__ __forceinline__ f16x8 cvt8(fv4 x0, fv4 x1) {
  f16x8 t;
  t[0]=(f16)x0[0]; t[1]=(f16)x0[1]; t[2]=(f16)x0[2]; t[3]=(f16)x0[3];
  t[4]=(f16)x1[0]; t[5]=(f16)x1[1]; t[6]=(f16)x1[2]; t[7]=(f16)x1[3];
  return t;
}

// ---- LDS staging with XOR swizzle (byte ^= (row&7)<<4) ----
template<int RB_LOG2, int SZ>
static __device__ __forceinline__ void load_weights(const f16* __restrict__ gw, char* lds) {
  const char* src = (const char*)gw;
#pragma unroll
  for (int g = threadIdx.x; g < SZ / 16; g += 256) {
    int byte = g << 4;
    int row  = byte >> RB_LOG2;
    int dstb = byte ^ ((row & 7) << 4);
    f16x8 v = *(const f16x8_a*)(src + byte);
    *(f16x8_a*)(lds + dstb) = v;
  }
}

template<int RB_LOG2>
static __device__ __forceinline__ f16x8 read_b(const char* lds, int n, int kbyte) {
  int byte = ((n << RB_LOG2) + kbyte) ^ ((n & 7) << 4);
  return *(const f16x8_a*)(lds + byte);
}

// per-wave activation tile: 32 rows x 128 f16 (256B rows), swizzled
static __device__ __forceinline__ f16x8 act_read(const char* act, int base, int m, int kbyte) {
  int byte = (base + m * 256 + kbyte) ^ ((m & 7) << 4);
  return *(const f16x8_a*)(act + byte);
}

static __device__ __forceinline__ void act_write(char* act, int base, int m, int col, f16 v) {
  int byte = (base + m * 256 + col * 2) ^ ((m & 7) << 4);
  *(f16_a*)(act + byte) = v;
}

// ---------------- fused prep: all weight transposes ----------------
__global__ void prep_transpose(const float* __restrict__ Wn1, const float* __restrict__ Wn2,
                               const float* __restrict__ We1, const float* __restrict__ Wp1,
                               const float* __restrict__ Wp2,
                               f16* __restrict__ WnT1, f16* __restrict__ WnT2,
                               f16* __restrict__ WeT1, f16* __restrict__ WaT,
                               f16* __restrict__ WbT,  f16* __restrict__ WpT2) {
  int b = blockIdx.x, t = threadIdx.x;
  if (b < 64)       { int i = b * 256 + t;        int n = i >> 7, k = i & 127; WnT1[i] = (f16)Wn1[(size_t)k * 128 + n]; }
  else if (b < 128) { int i = (b - 64) * 256 + t; int n = i >> 7, k = i & 127; WnT2[i] = (f16)Wn2[(size_t)k * 128 + n]; }
  else if (b < 136) { int i = (b - 128) * 256 + t; int n = i >> 4, k = i & 15; WeT1[i] = (f16)We1[(size_t)k * 128 + n]; }
  else if (b < 200) { int i = (b - 136) * 256 + t; int n = i >> 7, k = i & 127; WaT[i] = (f16)Wp1[(size_t)k * 128 + n]; }
  else if (b < 264) { int i = (b - 200) * 256 + t; int n = i >> 7, k = i & 127; WbT[i] = (f16)Wp1[(size_t)(128 + k) * 128 + n]; }
  else              { int i = (b - 264) * 256 + t; int n = i >> 7, k = i & 127; WpT2[i] = (f16)Wp2[(size_t)k * 64 + n]; }
}

// ---------------- fused prep: WC = We2@Wp1c (transposed) + bfold ----------------
__global__ void prep_fold(const float* __restrict__ We2, const float* __restrict__ Wp1,
                          const float* __restrict__ bp1, const float* __restrict__ be2,
                          f16* __restrict__ WCT, float* __restrict__ bfold) {
  int b = blockIdx.x, t = threadIdx.x;
  if (b < 64) {
    int i = b * 256 + t;
    int n = i >> 7, k = i & 127;
    float s = 0.f;
#pragma unroll 8
    for (int m = 0; m < 128; ++m)
      s += We2[(size_t)k * 128 + m] * Wp1[(size_t)(256 + m) * 128 + n];
    WCT[i] = (f16)s;
  } else if (t < 128) {
    float s = bp1[t];
#pragma unroll 8
    for (int m = 0; m < 128; ++m)
      s += be2[m] * Wp1[(size_t)(256 + m) * 128 + t];
    bfold[t] = s;
  }
}

// ---------------- node encoder: nf -> relu(@Wn1+bn1) -> @Wn2+bn2 -> emb (f16) ----------------
__global__ __launch_bounds__(256, 2) void node_kernel(
    const float* __restrict__ nf, const f16* __restrict__ WnT1, const float* __restrict__ bn1,
    const f16* __restrict__ WnT2, const float* __restrict__ bn2, f16* __restrict__ emb) {
  __shared__ char wbuf[32768];
  __shared__ char act[32768];
  const int tid = threadIdx.x, w = tid >> 6, lane = tid & 63;
  const int c = lane & 15, kb = lane >> 4;
  const int base = blockIdx.x * 128 + w * 32;
  const int abase = w * 8192;

  load_weights<8, 32768>(WnT1, wbuf);
  __syncthreads();

  {
    f16x8 a[2][4];
#pragma unroll
    for (int rt = 0; rt < 2; ++rt) {
      int r = base + rt * 16 + c; r = r < NN ? r : 0;
      const fv4* p = (const fv4*)(nf + (size_t)r * 128 + kb * 8);
#pragma unroll
      for (int ks = 0; ks < 4; ++ks) {
        fv4 x0 = __builtin_nontemporal_load(p + ks * 8);
        fv4 x1 = __builtin_nontemporal_load(p + ks * 8 + 1);
        a[rt][ks] = cvt8(x0, x1);
      }
    }
    f32x4 acc[2][8];
#pragma unroll
    for (int nt = 0; nt < 8; ++nt) {
      float bb = bn1[nt * 16 + c];
      acc[0][nt] = f32x4{bb, bb, bb, bb};
      acc[1][nt] = f32x4{bb, bb, bb, bb};
    }
#pragma unroll
    for (int ks = 0; ks < 4; ++ks)
#pragma unroll
      for (int nt = 0; nt < 8; ++nt) {
        f16x8 b = read_b<8>(wbuf, nt * 16 + c, ks * 64 + kb * 16);
        acc[0][nt] = mfma16(a[0][ks], b, acc[0][nt]);
        acc[1][nt] = mfma16(a[1][ks], b, acc[1][nt]);
      }
#pragma unroll
    for (int rt = 0; rt < 2; ++rt)
#pragma unroll
      for (int nt = 0; nt < 8; ++nt)
#pragma unroll
        for (int r = 0; r < 4; ++r) {
          float v = acc[rt][nt][r];
          v = v > 0.f ? v : 0.f;
          act_write(act, abase, rt * 16 + kb * 4 + r, nt * 16 + c, (f16)v);
        }
  }

  __syncthreads();
  load_weights<8, 32768>(WnT2, wbuf);
  __syncthreads();

  {
    f32x4 acc[2][8];
#pragma unroll
    for (int nt = 0; nt < 8; ++nt) {
      float bb = bn2[nt * 16 + c];
      acc[0][nt] = f32x4{bb, bb, bb, bb};
      acc[1][nt] = f32x4{bb, bb, bb, bb};
    }
#pragma unroll
    for (int ks = 0; ks < 4; ++ks) {
      f16x8 a0 = act_read(act, abase, c,      ks * 64 + kb * 16);
      f16x8 a1 = act_read(act, abase, 16 + c, ks * 64 + kb * 16);
#pragma unroll
      for (int nt = 0; nt < 8; ++nt) {
        f16x8 b = read_b<8>(wbuf, nt * 16 + c, ks * 64 + kb * 16);
        acc[0][nt] = mfma16(a0, b, acc[0][nt]);
        acc[1][nt] = mfma16(a1, b, acc[1][nt]);
      }
    }
#pragma unroll
    for (int rt = 0; rt < 2; ++rt)
#pragma unroll
      for (int nt = 0; nt < 8; ++nt)
#pragma unroll
        for (int r = 0; r < 4; ++r) {
          int row = base + rt * 16 + kb * 4 + r;
          if (row < NN) emb[(size_t)row * 128 + nt * 16 + c] = (f16)acc[rt][nt][r];
        }
  }
}

// ---------------- persistent fused edge kernel, tile-deep pipeline ----------------
struct Tile {
  int s0, s1, d0, d1;
  fv4 e00, e01, e10, e11;
  f16x8 ga0[4], ga1[4], gb0[4], gb1[4];
};

__global__ __launch_bounds__(256, 1) void edge_kernel(
    const float* __restrict__ ef, const int* __restrict__ eidx,
    const f16* __restrict__ WeT1, const float* __restrict__ be1,
    const f16* __restrict__ WaT, const f16* __restrict__ WbT,
    const f16* __restrict__ WCT, const f16* __restrict__ WpT2g,
    const float* __restrict__ bfold, const float* __restrict__ bp2,
    const float* __restrict__ Wp3, const float* __restrict__ bp3,
    const f16* __restrict__ emb, float* __restrict__ out) {
  __shared__ char wa[32768];
  __shared__ char wb[32768];
  __shared__ char wc[32768];
  __shared__ char wp2l[16384];
  __shared__ char act[32768];
  const int tid = threadIdx.x, w = tid >> 6, lane = tid & 63;
  const int c = lane & 15, kb = lane >> 4;
  const int abase = w * 8192;

  load_weights<8, 32768>(WaT, wa);
  load_weights<8, 32768>(WbT, wb);
  load_weights<8, 32768>(WCT, wc);
  load_weights<8, 16384>(WpT2g, wp2l);
  __syncthreads();   // only barrier

  // hoisted invariants
  f16x8 w1frag[8];
  float bias_e1[8], bias_p1[8], bias_p2[4], w3[4];
#pragma unroll
  for (int nt = 0; nt < 8; ++nt) {
    w1frag[nt] = *(const f16x8_a*)(WeT1 + (nt * 16 + c) * 16 + (kb & 1) * 8);
    bias_e1[nt] = be1[nt * 16 + c];
    bias_p1[nt] = bfold[nt * 16 + c];
  }
#pragma unroll
  for (int nt = 0; nt < 4; ++nt) { bias_p2[nt] = bp2[nt * 16 + c]; w3[nt] = Wp3[nt * 16 + c]; }
  const float b3 = bp3[0];

  auto LOAD_IDX = [&](int t, Tile& T) {
    int e0 = t * 32 + c;
    T.s0 = __builtin_nontemporal_load(eidx + e0);
    T.s1 = __builtin_nontemporal_load(eidx + e0 + 16);
    T.d0 = __builtin_nontemporal_load(eidx + NE + e0);
    T.d1 = __builtin_nontemporal_load(eidx + NE + e0 + 16);
  };
  auto LOAD_EF = [&](int t, Tile& T) {
    if (kb < 2) {
      const fv4* p = (const fv4*)(ef + (size_t)(t * 32 + c) * 16 + kb * 8);
      T.e00 = __builtin_nontemporal_load(p);
      T.e01 = __builtin_nontemporal_load(p + 1);
      const fv4* q = (const fv4*)(ef + (size_t)(t * 32 + 16 + c) * 16 + kb * 8);
      T.e10 = __builtin_nontemporal_load(q);
      T.e11 = __builtin_nontemporal_load(q + 1);
    }
  };
  auto LOAD_G = [&](Tile& T) {
    const f16* p0 = emb + (size_t)T.s0 * 128 + kb * 8;
    const f16* p1 = emb + (size_t)T.s1 * 128 + kb * 8;
    const f16* q0 = emb + (size_t)T.d0 * 128 + kb * 8;
    const f16* q1 = emb + (size_t)T.d1 * 128 + kb * 8;
#pragma unroll
    for (int ks = 0; ks < 4; ++ks) {
      T.ga0[ks] = *(const f16x8_a*)(p0 + ks * 32);
      T.ga1[ks] = *(const f16x8_a*)(p1 + ks * 32);
      T.gb0[ks] = *(const f16x8_a*)(q0 + ks * 32);
      T.gb1[ks] = *(const f16x8_a*)(q1 + ks * 32);
    }
  };

  auto BODY = [&](int t, Tile& C0, Tile& N0, int pft) {
    // prefetch next tile's idx + edge features early
    LOAD_IDX(pft, N0);
    LOAD_EF(pft, N0);

    // ---- E1: h1e = relu(ef @ We1 + be1) ----
    {
      f16x8 ae0 = zero8(), ae1 = zero8();
      if (kb < 2) { ae0 = cvt8(C0.e00, C0.e01); ae1 = cvt8(C0.e10, C0.e11); }
      f32x4 acc1[2][8];
#pragma unroll
      for (int nt = 0; nt < 8; ++nt) {
        acc1[0][nt] = f32x4{bias_e1[nt], bias_e1[nt], bias_e1[nt], bias_e1[nt]};
        acc1[1][nt] = acc1[0][nt];
      }
#pragma unroll
      for (int nt = 0; nt < 8; ++nt) {
        acc1[0][nt] = mfma16(ae0, w1frag[nt], acc1[0][nt]);
        acc1[1][nt] = mfma16(ae1, w1frag[nt], acc1[1][nt]);
      }
#pragma unroll
      for (int rt = 0; rt < 2; ++rt)
#pragma unroll
        for (int nt = 0; nt < 8; ++nt)
#pragma unroll
          for (int r = 0; r < 4; ++r) {
            float v = acc1[rt][nt][r];
            v = v > 0.f ? v : 0.f;
            act_write(act, abase, rt * 16 + kb * 4 + r, nt * 16 + c, (f16)v);
          }
    }

    // ---- P1 accumulator: bfold + h1e@WC + emb_s@Wp1a + emb_d@Wp1b ----
    f32x4 accp[2][8];
#pragma unroll
    for (int nt = 0; nt < 8; ++nt) {
      accp[0][nt] = f32x4{bias_p1[nt], bias_p1[nt], bias_p1[nt], bias_p1[nt]};
      accp[1][nt] = accp[0][nt];
    }
    // PE: h1e @ WC
#pragma unroll
    for (int ks = 0; ks < 4; ++ks) {
      f16x8 a0 = act_read(act, abase, c,      ks * 64 + kb * 16);
      f16x8 a1 = act_read(act, abase, 16 + c, ks * 64 + kb * 16);
#pragma unroll
      for (int nt = 0; nt < 8; ++nt) {
        f16x8 b = read_b<8>(wc, nt * 16 + c, ks * 64 + kb * 16);
        accp[0][nt] = mfma16(a0, b, accp[0][nt]);
        accp[1][nt] = mfma16(a1, b, accp[1][nt]);
      }
    }

    // issue next tile's gathers now (idx has arrived; covered by P1a..P2 compute)
    LOAD_G(N0);

    // P1a: emb[src] @ Wp1a
#pragma unroll
    for (int ks = 0; ks < 4; ++ks)
#pragma unroll
      for (int nt = 0; nt < 8; ++nt) {
        f16x8 b = read_b<8>(wa, nt * 16 + c, ks * 64 + kb * 16);
        accp[0][nt] = mfma16(C0.ga0[ks], b, accp[0][nt]);
        accp[1][nt] = mfma16(C0.ga1[ks], b, accp[1][nt]);
      }
    // P1b: emb[dst] @ Wp1b
#pragma unroll
    for (int ks = 0; ks < 4; ++ks)
#pragma unroll
      for (int nt = 0; nt < 8; ++nt) {
        f16x8 b = read_b<8>(wb, nt * 16 + c, ks * 64 + kb * 16);
        accp[0][nt] = mfma16(C0.gb0[ks], b, accp[0][nt]);
        accp[1][nt] = mfma16(C0.gb1[ks], b, accp[1][nt]);
      }

    // relu -> act
#pragma unroll
    for (int rt = 0; rt < 2; ++rt)
#pragma unroll
      for (int nt = 0; nt < 8; ++nt)
#pragma unroll
        for (int r = 0; r < 4; ++r) {
          float v = accp[rt][nt][r];
          v = v > 0.f ? v : 0.f;
          act_write(act, abase, rt * 16 + kb * 4 + r, nt * 16 + c, (f16)v);
        }

    // ---- P2 ----
    f32x4 accq[2][4];
#pragma unroll
    for (int nt = 0; nt < 4; ++nt) {
      accq[0][nt] = f32x4{bias_p2[nt], bias_p2[nt], bias_p2[nt], bias_p2[nt]};
      accq[1][nt] = accq[0][nt];
    }
#pragma unroll
    for (int ks = 0; ks < 4; ++ks) {
      f16x8 a0 = act_read(act, abase, c,      ks * 64 + kb * 16);
      f16x8 a1 = act_read(act, abase, 16 + c, ks * 64 + kb * 16);
#pragma unroll
      for (int nt = 0; nt < 4; ++nt) {
        f16x8 b = read_b<8>(wp2l, nt * 16 + c, ks * 64 + kb * 16);
        accq[0][nt] = mfma16(a0, b, accq[0][nt]);
        accq[1][nt] = mfma16(a1, b, accq[1][nt]);
      }
    }

    // ---- P3: relu, dot Wp3, sigmoid, NT store ----
#pragma unroll
    for (int rt = 0; rt < 2; ++rt) {
#pragma unroll
      for (int r = 0; r < 4; ++r) {
        float s = 0.f;
#pragma unroll
        for (int nt = 0; nt < 4; ++nt) {
          float h = accq[rt][nt][r];
          h = h > 0.f ? h : 0.f;
          s += h * w3[nt];
        }
        s += __shfl_xor(s, 1, 64);
        s += __shfl_xor(s, 2, 64);
        s += __shfl_xor(s, 4, 64);
        s += __shfl_xor(s, 8, 64);
        if (c == r) {
          int m = t * 32 + rt * 16 + kb * 4 + r;
          float v = 1.f / (1.f + __expf(-(s + b3)));
          __builtin_nontemporal_store(v, out + m);
        }
      }
    }
  };

  const int gw = blockIdx.x * 4 + w;
  Tile A, B;
  LOAD_IDX(gw, A);
  LOAD_EF(gw, A);
  LOAD_G(A);

  for (int t = gw; t < NT_TILES; t += 2 * NW) {
    int t1 = t + NW;
    BODY(t, A, B, t1 < NT_TILES ? t1 : t);
    if (t1 < NT_TILES) {
      int t2 = t1 + NW;
      BODY(t1, B, A, t2 < NT_TILES ? t2 : t1);
    }
  }
}

extern "C" void kernel_launch(void* const* d_in, const int* in_sizes, int n_in,
                              void* d_out, int out_size, void* d_ws, size_t ws_size,
                              hipStream_t stream) {
  const float* nf  = (const float*)d_in[0];
  const int*   ei  = (const int*)  d_in[1];
  const float* ef  = (const float*)d_in[2];
  const float* Wn1 = (const float*)d_in[3];
  const float* bn1 = (const float*)d_in[4];
  const float* Wn2 = (const float*)d_in[5];
  const float* bn2 = (const float*)d_in[6];
  const float* We1 = (const float*)d_in[7];
  const float* be1 = (const float*)d_in[8];
  const float* We2 = (const float*)d_in[9];
  const float* be2 = (const float*)d_in[10];
  const float* Wp1 = (const float*)d_in[11];
  const float* bp1 = (const float*)d_in[12];
  const float* Wp2 = (const float*)d_in[13];
  const float* bp2 = (const float*)d_in[14];
  const float* Wp3 = (const float*)d_in[15];
  const float* bp3 = (const float*)d_in[16];

  char* ws = (char*)d_ws;
  f16*   WnT1  = (f16*)(ws);                 // 32768
  f16*   WnT2  = (f16*)(ws + 32768);         // 32768
  f16*   WeT1  = (f16*)(ws + 65536);         // 4096
  f16*   WaT   = (f16*)(ws + 69632);         // 32768
  f16*   WbT   = (f16*)(ws + 102400);        // 32768
  f16*   WCT   = (f16*)(ws + 135168);        // 32768
  f16*   WpT2  = (f16*)(ws + 167936);        // 16384
  float* bfold = (float*)(ws + 184320);      // 512
  f16*   emb   = (f16*)(ws + 184832);        // 25,600,000

  prep_transpose<<<296, 256, 0, stream>>>(Wn1, Wn2, We1, Wp1, Wp2,
                                          WnT1, WnT2, WeT1, WaT, WbT, WpT2);
  prep_fold<<<65, 256, 0, stream>>>(We2, Wp1, bp1, be2, WCT, bfold);
  node_kernel<<<782, 256, 0, stream>>>(nf, WnT1, bn1, WnT2, bn2, emb);
  edge_kernel<<<EK_BLOCKS, 256, 0, stream>>>(ef, ei, WeT1, be1, WaT, WbT, WCT, WpT2,
                                             bfold, bp2, Wp3, bp3, emb, (float*)d_out);
}